// Round 6
// baseline (91.904 us; speedup 1.0000x reference)
//
#include <hip/hip_runtime.h>
#include <hip/hip_bf16.h>

#define S_LEN 2048
#define D_DIM 64
#define NHEADS 48
#define QT 128
#define KT 32
#define NKT (S_LEN / KT)     // 64
#define HEAD_ELEMS ((size_t)S_LEN * D_DIM)
#define WS_NEED (3ull * NHEADS * S_LEN * D_DIM * 2ull)

typedef short bf16x8 __attribute__((ext_vector_type(8)));
typedef float f32x4 __attribute__((ext_vector_type(4)));

// fp32 -> bf16 round-to-nearest-even (finite inputs only)
__device__ __forceinline__ unsigned short f2bf(float x) {
    unsigned u = __builtin_bit_cast(unsigned, x);
    u = (u + 0x7fffu + ((u >> 16) & 1u)) >> 16;
    return (unsigned short)u;
}

// packed fp32x2 -> bf16x2 (1 instruction, RTNE)
__device__ __forceinline__ unsigned cvtpk(float lo, float hi) {
    unsigned r;
    asm("v_cvt_pk_bf16_f32 %0, %1, %2" : "=v"(r) : "v"(lo), "v"(hi));
    return r;
}

// ---------------- pre-pass: fp32 -> bf16, MFMA-fragment layouts baked ----------------
// Qs : row-major, scaled by log2e/T.
// Kf : per 32x64 K-tile, fragment order: elem K[f*16+l15][c*32+lhi*8+j] at
//      tile*2048 + c*1024 + f*512 + (lhi*16+l15)*8 + j    (ushort units, f in {0,1})
// Vf : per 32-k tile, V^T fragment order with PV k-slot permutation
//      pi(lhi,j)=(j>>2)*16+lhi*4+(j&3):
//      elem V^T[g*16+l15][pi] at tile*2048 + g*512 + (lhi*16+l15)*8 + j
__global__ __launch_bounds__(256) void lsa_prep(
    const float* __restrict__ Qg, const float* __restrict__ Kg,
    const float* __restrict__ Vg, const float* __restrict__ Tg,
    unsigned short* __restrict__ Qs, unsigned short* __restrict__ Kf,
    unsigned short* __restrict__ Vf) {
    const int b   = blockIdx.x;      // 64-row chunk index (h*32 + chunk)
    const int tid = threadIdx.x;
    const int r   = tid >> 4;        // 0..15
    const int c4  = (tid & 15) * 4;  // 0..60

    __shared__ __align__(16) unsigned short Kl[4096];
    __shared__ __align__(16) unsigned short Vl[4096];

    const size_t ibase = (size_t)b * 4096;
    const float qscale = 1.442695041f / Tg[0];

#pragma unroll
    for (int it = 0; it < 4; ++it) {
        const int rr = it * 16 + r;                   // chunk-local k-row 0..63
        const size_t off = ibase + (size_t)rr * D_DIM + c4;

        float4 q4 = *(const float4*)(Qg + off);
        uint2 qo;
        qo.x = cvtpk(q4.x * qscale, q4.y * qscale);
        qo.y = cvtpk(q4.z * qscale, q4.w * qscale);
        *(uint2*)&Qs[off] = qo;

        float4 k4 = *(const float4*)(Kg + off);
        {
            const int l15 = rr & 15;
            const int c = c4 >> 5, lhi = (c4 >> 3) & 3, j0 = c4 & 7;
            uint2 ko;
            ko.x = cvtpk(k4.x, k4.y);
            ko.y = cvtpk(k4.z, k4.w);
            *(uint2*)&Kl[(rr >> 5) * 2048 + c * 1024 + ((rr >> 4) & 1) * 512
                         + ((lhi << 4) | l15) * 8 + j0] = ko;
        }

        float4 v4 = *(const float4*)(Vg + off);
        {
            // V^T element: d = c4+i, k = rr (tile = rr>>5, rem in [0,32))
            const int cc = rr >> 5, rem = rr & 31;
            const int jv = ((rem >> 4) << 2) | (rem & 3);
            const int lhiv = (rem >> 2) & 3;
            const int g = c4 >> 4;
            const int base = cc * 2048 + g * 512 + (lhiv << 7) + jv;
            Vl[base + ((c4 + 0) & 15) * 8] = f2bf(v4.x);
            Vl[base + ((c4 + 1) & 15) * 8] = f2bf(v4.y);
            Vl[base + ((c4 + 2) & 15) * 8] = f2bf(v4.z);
            Vl[base + ((c4 + 3) & 15) * 8] = f2bf(v4.w);
        }
    }
    __syncthreads();
    const uint4* ks = (const uint4*)Kl;
    const uint4* vs = (const uint4*)Vl;
    uint4* kd = (uint4*)(Kf + ibase);
    uint4* vd = (uint4*)(Vf + ibase);
    kd[tid]       = ks[tid];
    kd[tid + 256] = ks[tid + 256];
    vd[tid]       = vs[tid];
    vd[tid + 256] = vs[tid + 256];
}

// ---------------- main kernel: zero LDS, S-double-buffered software pipeline ----------------
__global__ __launch_bounds__(256, 3) void lsa_attn_p2(
    const unsigned short* __restrict__ Qs, const unsigned short* __restrict__ Kf,
    const unsigned short* __restrict__ Vf, float* __restrict__ Og) {

    const int bid  = blockIdx.x;
    const int xcd  = bid & 7;             // 6 heads per XCD for L2 locality
    const int idx  = bid >> 3;            // 0..95
    const int bh   = xcd * 6 + (idx >> 4);
    const int qt   = idx & 15;
    const int tid  = threadIdx.x;
    const int wid  = tid >> 6;
    const int lane = tid & 63;
    const int l15  = lane & 15;
    const int lhi  = lane >> 4;

    const unsigned short* Qh = Qs + (size_t)bh * HEAD_ELEMS;
    const char* Kh = (const char*)(Kf + (size_t)bh * HEAD_ELEMS) + lane * 16;
    const char* Vh = (const char*)(Vf + (size_t)bh * HEAD_ELEMS) + lane * 16;
    float* Ob = Og + (size_t)bh * HEAD_ELEMS;

    const int qbase   = qt * QT + wid * 32;
    const int diag_kt = qbase >> 5;       // 32-row K-tiles

    // Q fragments (B-operand of mfma(K,Q))
    bf16x8 qf[2][2];
#pragma unroll
    for (int rb = 0; rb < 2; ++rb) {
#pragma unroll
        for (int c = 0; c < 2; ++c) {
            qf[rb][c] = *(const bf16x8*)(Qh + (size_t)(qbase + rb * 16 + l15) * D_DIM
                                            + c * 32 + lhi * 8);
        }
    }

    const f32x4 zero4 = {0.f, 0.f, 0.f, 0.f};
    f32x4 acc[2][4];
    float mrow[2], lp[2];
#pragma unroll
    for (int rb = 0; rb < 2; ++rb) {
#pragma unroll
        for (int g = 0; g < 4; ++g) acc[rb][g] = zero4;
        mrow[rb] = -1e30f; lp[rb] = 0.f;
    }

    bf16x8 kr[4], vr[4], pb[2];           // single-buffered operands (static names)
    f32x4 sfA[2][2], sfB[2][2];           // double-buffered S (T15)

#define LOADK(T) do {                                                          \
    const char* p_ = Kh + (size_t)(T) * 4096;                                  \
    _Pragma("unroll")                                                          \
    for (int u = 0; u < 4; ++u) {                                              \
        kr[u] = *(const bf16x8*)(p_ + (u >> 1) * 2048 + (u & 1) * 1024);       \
    }                                                                          \
} while (0)

#define LOADV(T) do {                                                          \
    const char* p_ = Vh + (size_t)(T) * 4096;                                  \
    _Pragma("unroll")                                                          \
    for (int g = 0; g < 4; ++g) {                                              \
        vr[g] = *(const bf16x8*)(p_ + g * 1024);                               \
    }                                                                          \
} while (0)

// S^T(tile) = K Q^T : SF[rb][f], row k = f*16+lhi*4+i, col q = rb*16+l15
#define QK(SF) do {                                                            \
    _Pragma("unroll")                                                          \
    for (int rb = 0; rb < 2; ++rb) {                                           \
        _Pragma("unroll")                                                      \
        for (int f = 0; f < 2; ++f) SF[rb][f] = zero4;                         \
    }                                                                          \
    __builtin_amdgcn_s_setprio(1);                                             \
    _Pragma("unroll")                                                          \
    for (int c = 0; c < 2; ++c) {                                              \
        _Pragma("unroll")                                                      \
        for (int rb = 0; rb < 2; ++rb) {                                       \
            _Pragma("unroll")                                                  \
            for (int f = 0; f < 2; ++f) {                                      \
                SF[rb][f] = __builtin_amdgcn_mfma_f32_16x16x32_bf16(           \
                    kr[c * 2 + f], qf[rb][c], SF[rb][f], 0, 0, 0);             \
            }                                                                  \
        }                                                                      \
    }                                                                          \
    __builtin_amdgcn_s_setprio(0);                                             \
} while (0)

#define PV() do {                                                              \
    __builtin_amdgcn_s_setprio(1);                                             \
    _Pragma("unroll")                                                          \
    for (int rb = 0; rb < 2; ++rb) {                                           \
        _Pragma("unroll")                                                      \
        for (int g = 0; g < 4; ++g) {                                          \
            acc[rb][g] = __builtin_amdgcn_mfma_f32_16x16x32_bf16(              \
                vr[g], pb[rb], acc[rb][g], 0, 0, 0);                           \
        }                                                                      \
    }                                                                          \
    __builtin_amdgcn_s_setprio(0);                                             \
} while (0)

#define SMX(T, SF) do {                                                        \
    if ((T) == diag_kt) {                                                      \
        _Pragma("unroll")                                                      \
        for (int rb = 0; rb < 2; ++rb) {                                       \
            const int q_ = qbase + rb * 16 + l15;                              \
            _Pragma("unroll")                                                  \
            for (int f = 0; f < 2; ++f) {                                      \
                _Pragma("unroll")                                              \
                for (int i = 0; i < 4; ++i) {                                  \
                    const int k_ = (T) * KT + f * 16 + lhi * 4 + i;            \
                    if (q_ == k_) SF[rb][f][i] = -1e30f;                       \
                }                                                              \
            }                                                                  \
        }                                                                      \
    }                                                                          \
    _Pragma("unroll")                                                          \
    for (int rb = 0; rb < 2; ++rb) {                                           \
        const float pm_ = fmaxf(                                               \
            fmaxf(fmaxf(SF[rb][0][0], SF[rb][0][1]),                           \
                  fmaxf(SF[rb][0][2], SF[rb][0][3])),                          \
            fmaxf(fmaxf(SF[rb][1][0], SF[rb][1][1]),                           \
                  fmaxf(SF[rb][1][2], SF[rb][1][3])));                         \
        if (__any(pm_ > mrow[rb] + 8.0f)) {                                    \
            float m0_ = pm_;                                                   \
            m0_ = fmaxf(m0_, __shfl_xor(m0_, 16));                             \
            m0_ = fmaxf(m0_, __shfl_xor(m0_, 32));                             \
            const float mnew_ = fmaxf(mrow[rb], m0_);                          \
            const float al_ = __builtin_amdgcn_exp2f(mrow[rb] - mnew_);        \
            mrow[rb] = mnew_;                                                  \
            lp[rb] *= al_;                                                     \
            _Pragma("unroll")                                                  \
            for (int g = 0; g < 4; ++g) acc[rb][g] *= al_;                     \
        }                                                                      \
        f32x4 ps_ = zero4;                                                     \
        _Pragma("unroll")                                                      \
        for (int f = 0; f < 2; ++f) {                                          \
            _Pragma("unroll")                                                  \
            for (int i = 0; i < 4; ++i) {                                      \
                SF[rb][f][i] = __builtin_amdgcn_exp2f(SF[rb][f][i] - mrow[rb]); \
            }                                                                  \
            ps_ += SF[rb][f];                                                  \
        }                                                                      \
        lp[rb] += (ps_[0] + ps_[1]) + (ps_[2] + ps_[3]);                       \
        uint4 u_;                                                              \
        u_.x = cvtpk(SF[rb][0][0], SF[rb][0][1]);                              \
        u_.y = cvtpk(SF[rb][0][2], SF[rb][0][3]);                              \
        u_.z = cvtpk(SF[rb][1][0], SF[rb][1][1]);                              \
        u_.w = cvtpk(SF[rb][1][2], SF[rb][1][3]);                              \
        pb[rb] = __builtin_bit_cast(bf16x8, u_);                               \
    }                                                                          \
} while (0)

    // ---- pipeline prologue ----
    LOADK(0);
    QK(sfA);          // S(0)
    LOADK(1);
    LOADV(0);

    // steady state, unroll-2 (static buffer names, rule #20)
#pragma unroll 1
    for (int t = 0; t < NKT - 2; t += 2) {
        // even phase: QK(t+1) overlaps SM(t) (independent: sfB vs sfA)
        QK(sfB);                 // S(t+1) from kr=K(t+1)
        LOADK(t + 2);            // WAR after QK reads kr
        SMX(t, sfA);             // VALU, overlaps QK's MFMA execution
        PV();                    // O += V(t) P(t)
        LOADV(t + 1);
        // odd phase
        QK(sfA);                 // S(t+2) from kr=K(t+2)
        LOADK(t + 3);            // t+3 <= NKT-1 for t <= NKT-4
        SMX(t + 1, sfB);
        PV();                    // O += V(t+1) P(t+1)
        LOADV(t + 2);
    }
    // epilogue: sfA = S(NKT-2), kr = K(NKT-1), vr = V(NKT-2)
    QK(sfB);                     // S(NKT-1)
    SMX(NKT - 2, sfA);
    PV();
    LOADV(NKT - 1);
    SMX(NKT - 1, sfB);
    PV();

#undef LOADK
#undef LOADV
#undef QK
#undef PV
#undef SMX

    // ---- epilogue: reduce partial sums across the row's 4 lanes, store fp32
#pragma unroll
    for (int rb = 0; rb < 2; ++rb) {
        float l = lp[rb];
        l += __shfl_xor(l, 16);
        l += __shfl_xor(l, 32);
        const float invl = 1.0f / l;
        const int q = qbase + rb * 16 + l15;
#pragma unroll
        for (int g = 0; g < 4; ++g) {
            float4 o;
            o.x = acc[rb][g][0] * invl;
            o.y = acc[rb][g][1] * invl;
            o.z = acc[rb][g][2] * invl;
            o.w = acc[rb][g][3] * invl;
            *(float4*)(Ob + (size_t)q * D_DIM + g * 16 + lhi * 4) = o;
        }
    }
}

// ---------------- fallback (round-2 kernel, used if ws too small) ----------------
__device__ __forceinline__ int swzK_fb(int row, int col) {
    return (row << 6) + (col ^ ((row & 7) << 3));
}
__device__ __forceinline__ int swzV_fb(int row, int col) {
    int f = (row ^ (row >> 3)) & 7;
    return (row << 6) + (col ^ (f << 3));
}

__global__ __launch_bounds__(256, 2) void lsa_attn_fb(
    const float* __restrict__ Qg, const float* __restrict__ Kg,
    const float* __restrict__ Vg, const float* __restrict__ Tg,
    float* __restrict__ Og) {

    const int bid  = blockIdx.x;
    const int bh   = bid >> 4;
    const int qt   = bid & 15;
    const int tid  = threadIdx.x;
    const int wid  = tid >> 6;
    const int lane = tid & 63;
    const int l15  = lane & 15;
    const int lhi  = lane >> 4;

    __shared__ __align__(16) unsigned short Kt[64 * D_DIM];
    __shared__ __align__(16) unsigned short Vt[D_DIM * 64];

    const size_t base = (size_t)bh * HEAD_ELEMS;
    const float* Qb = Qg + base;
    const float* Kb = Kg + base;
    const float* Vb = Vg + base;
    float*       Ob = Og + base;

    const float inv_t = 1.0f / Tg[0];
    const int qbase = qt * QT + wid * 32;
    const int diag_kt = qbase >> 6;

    bf16x8 qf[2][2];
#pragma unroll
    for (int rb = 0; rb < 2; ++rb) {
#pragma unroll
        for (int c = 0; c < 2; ++c) {
            const float* src = Qb + (size_t)(qbase + rb * 16 + l15) * D_DIM + c * 32 + lhi * 8;
            float4 a = *(const float4*)(src);
            float4 b = *(const float4*)(src + 4);
            bf16x8 v;
            v[0] = (short)f2bf(a.x * inv_t); v[1] = (short)f2bf(a.y * inv_t);
            v[2] = (short)f2bf(a.z * inv_t); v[3] = (short)f2bf(a.w * inv_t);
            v[4] = (short)f2bf(b.x * inv_t); v[5] = (short)f2bf(b.y * inv_t);
            v[6] = (short)f2bf(b.z * inv_t); v[7] = (short)f2bf(b.w * inv_t);
            qf[rb][c] = v;
        }
    }

    const f32x4 zero4 = {0.f, 0.f, 0.f, 0.f};
    f32x4 acc[2][4];
    float mrow[2], lrow[2];
#pragma unroll
    for (int rb = 0; rb < 2; ++rb) {
#pragma unroll
        for (int g = 0; g < 4; ++g) acc[rb][g] = zero4;
        mrow[rb] = -1e30f; lrow[rb] = 0.f;
    }

    const int ld_r = tid >> 4;
    const int ld_c = (tid & 15) * 4;
    float4 kreg[4], vreg[4];

#define LOAD_TILE(KT_IDX) do {                                                 \
    const int kb0_ = (KT_IDX) * 64;                                            \
    _Pragma("unroll")                                                          \
    for (int it = 0; it < 4; ++it) {                                           \
        const int r_ = it * 16 + ld_r;                                         \
        kreg[it] = *(const float4*)(Kb + (size_t)(kb0_ + r_) * D_DIM + ld_c);  \
        vreg[it] = *(const float4*)(Vb + (size_t)(kb0_ + r_) * D_DIM + ld_c);  \
    }                                                                          \
} while (0)

    LOAD_TILE(0);

    for (int kt = 0; kt < 32; ++kt) {
        const int kb0 = kt * 64;
        __syncthreads();
#pragma unroll
        for (int it = 0; it < 4; ++it) {
            const int r = it * 16 + ld_r;
            unsigned lo = (unsigned)f2bf(kreg[it].x) | ((unsigned)f2bf(kreg[it].y) << 16);
            unsigned hi = (unsigned)f2bf(kreg[it].z) | ((unsigned)f2bf(kreg[it].w) << 16);
            *(uint2*)&Kt[swzK_fb(r, ld_c)] = make_uint2(lo, hi);
            Vt[swzV_fb(ld_c + 0, r)] = f2bf(vreg[it].x);
            Vt[swzV_fb(ld_c + 1, r)] = f2bf(vreg[it].y);
            Vt[swzV_fb(ld_c + 2, r)] = f2bf(vreg[it].z);
            Vt[swzV_fb(ld_c + 3, r)] = f2bf(vreg[it].w);
        }
        __syncthreads();
        if (kt + 1 < 32) LOAD_TILE(kt + 1);

        f32x4 sf[2][4];
#pragma unroll
        for (int rb = 0; rb < 2; ++rb) {
#pragma unroll
            for (int f = 0; f < 4; ++f) sf[rb][f] = zero4;
        }

#pragma unroll
        for (int c = 0; c < 2; ++c) {
            bf16x8 kb[4];
#pragma unroll
            for (int f = 0; f < 4; ++f)
                kb[f] = *(const bf16x8*)&Kt[swzK_fb(f * 16 + l15, c * 32 + lhi * 8)];
#pragma unroll
            for (int rb = 0; rb < 2; ++rb) {
#pragma unroll
                for (int f = 0; f < 4; ++f)
                    sf[rb][f] = __builtin_amdgcn_mfma_f32_16x16x32_bf16(
                        kb[f], qf[rb][c], sf[rb][f], 0, 0, 0);
            }
        }

        if (kt == diag_kt) {
#pragma unroll
            for (int rb = 0; rb < 2; ++rb) {
                const int q = qbase + rb * 16 + l15;
#pragma unroll
                for (int f = 0; f < 4; ++f) {
#pragma unroll
                    for (int i = 0; i < 4; ++i) {
                        const int k = kb0 + f * 16 + lhi * 4 + i;
                        if (q == k) sf[rb][f][i] = -1e30f;
                    }
                }
            }
        }

        bf16x8 pb[2][2];
#pragma unroll
        for (int rb = 0; rb < 2; ++rb) {
            f32x4 mv;
#pragma unroll
            for (int i = 0; i < 4; ++i)
                mv[i] = fmaxf(fmaxf(sf[rb][0][i], sf[rb][1][i]),
                              fmaxf(sf[rb][2][i], sf[rb][3][i]));
            float m0 = fmaxf(fmaxf(mv[0], mv[1]), fmaxf(mv[2], mv[3]));
            m0 = fmaxf(m0, __shfl_xor(m0, 16));
            m0 = fmaxf(m0, __shfl_xor(m0, 32));
            const float mnew  = fmaxf(mrow[rb], m0);
            const float alpha = __expf(mrow[rb] - mnew);
            mrow[rb] = mnew;
            f32x4 ps = zero4;
#pragma unroll
            for (int f = 0; f < 4; ++f) {
#pragma unroll
                for (int i = 0; i < 4; ++i)
                    sf[rb][f][i] = __expf(sf[rb][f][i] - mnew);
                ps += sf[rb][f];
            }
            float s0 = (ps[0] + ps[1]) + (ps[2] + ps[3]);
            s0 += __shfl_xor(s0, 16);
            s0 += __shfl_xor(s0, 32);
            lrow[rb] = lrow[rb] * alpha + s0;
#pragma unroll
            for (int g = 0; g < 4; ++g) acc[rb][g] *= alpha;
#pragma unroll
            for (int cc = 0; cc < 2; ++cc) {
                bf16x8 v;
#pragma unroll
                for (int j = 0; j < 8; ++j)
                    v[j] = (short)f2bf(sf[rb][cc * 2 + (j >> 2)][j & 3]);
                pb[rb][cc] = v;
            }
        }

#pragma unroll
        for (int cc = 0; cc < 2; ++cc) {
            bf16x8 va[4];
#pragma unroll
            for (int g = 0; g < 4; ++g) {
                const int row = g * 16 + l15;
                uint2 lo = *(const uint2*)&Vt[swzV_fb(row, cc * 32 + lhi * 4)];
                uint2 hi = *(const uint2*)&Vt[swzV_fb(row, cc * 32 + 16 + lhi * 4)];
                bf16x8 t;
                ((uint2*)&t)[0] = lo;
                ((uint2*)&t)[1] = hi;
                va[g] = t;
            }
#pragma unroll
            for (int rb = 0; rb < 2; ++rb) {
#pragma unroll
                for (int g = 0; g < 4; ++g)
                    acc[rb][g] = __builtin_amdgcn_mfma_f32_16x16x32_bf16(
                        va[g], pb[rb][cc], acc[rb][g], 0, 0, 0);
            }
        }
    }
#undef LOAD_TILE

#pragma unroll
    for (int rb = 0; rb < 2; ++rb) {
        const float invl = 1.0f / lrow[rb];
        const int q = qbase + rb * 16 + l15;
#pragma unroll
        for (int g = 0; g < 4; ++g) {
            float4 o;
            o.x = acc[rb][g][0] * invl;
            o.y = acc[rb][g][1] * invl;
            o.z = acc[rb][g][2] * invl;
            o.w = acc[rb][g][3] * invl;
            *(float4*)(Ob + (size_t)q * D_DIM + g * 16 + lhi * 4) = o;
        }
    }
}

extern "C" void kernel_launch(void* const* d_in, const int* in_sizes, int n_in,
                              void* d_out, int out_size, void* d_ws, size_t ws_size,
                              hipStream_t stream) {
    const float* Q = (const float*)d_in[0];
    const float* K = (const float*)d_in[1];
    const float* V = (const float*)d_in[2];
    const float* T = (const float*)d_in[3];
    float* O = (float*)d_out;

    if (ws_size >= WS_NEED) {
        unsigned short* Qs = (unsigned short*)d_ws;
        unsigned short* Kf = Qs + NHEADS * HEAD_ELEMS;
        unsigned short* Vf = Kf + NHEADS * HEAD_ELEMS;
        hipLaunchKernelGGL(lsa_prep, dim3(NHEADS * 32), dim3(256), 0, stream,
                           Q, K, V, T, Qs, Kf, Vf);
        hipLaunchKernelGGL(lsa_attn_p2, dim3(NHEADS * (S_LEN / QT)), dim3(256), 0, stream,
                           Qs, Kf, Vf, O);
    } else {
        hipLaunchKernelGGL(lsa_attn_fb, dim3(NHEADS * (S_LEN / QT)), dim3(256), 0, stream,
                           Q, K, V, T, O);
    }
}